// Round 2
// baseline (79.294 us; speedup 1.0000x reference)
//
#include <hip/hip_runtime.h>

// Gravity field: F[b,i,:] = G * m_i * mask_i * sum_j (m_j*mask_j) * (p_j - p_i) / max(|p_j-p_i|, 1e-4)^3
// Diagonal term is identically zero because diff == 0 exactly (no branch needed).
// max(sqrt(r2), eps) == sqrt(max(r2, eps*eps)) -> single v_rsq_f32 + clamp.
// __builtin_amdgcn_rsqf forces a bare v_rsq_f32 (no OCML denorm fixup code).

#define TI  256   // threads per block
#define IPT 2     // i-values per thread
#define TJ  128   // bodies-j per block (staged in LDS)

__global__ __launch_bounds__(TI) void gravity_kernel(
    const float* __restrict__ pos,    // (B, N, 3)
    const float* __restrict__ mass,   // (B, N, 1)
    const float* __restrict__ Gp,     // (1,)
    const float* __restrict__ mask,   // (B, N)
    float* __restrict__ out,          // (B, N, 3) -- pre-zeroed
    int N, int jsplit)
{
    __shared__ float4 sj[TJ];

    const int ib      = TI * IPT;            // i-values per block (512)
    const int tiles_i = N / ib;              // 8
    const int per_b   = tiles_i * jsplit;
    const int bid     = blockIdx.x;
    const int b       = bid / per_b;
    const int rem     = bid - b * per_b;
    const int it      = rem / jsplit;
    const int jc      = rem - it * jsplit;
    const int tid     = threadIdx.x;
    const int i0      = it * ib + tid;       // first i
    const int i1      = i0 + TI;             // second i

    const float* posb  = pos  + (size_t)b * N * 3;
    const float* massb = mass + (size_t)b * N;
    const float* maskb = mask + (size_t)b * N;

    // Stage j-tile: position + (mass*mask) packed as float4.
    if (tid < TJ) {
        const int j = jc * TJ + tid;
        float4 v;
        v.x = posb[j * 3 + 0];
        v.y = posb[j * 3 + 1];
        v.z = posb[j * 3 + 2];
        v.w = massb[j] * maskb[j];
        sj[tid] = v;
    }

    const float g = Gp[0];
    const float pix0 = posb[i0 * 3 + 0], piy0 = posb[i0 * 3 + 1], piz0 = posb[i0 * 3 + 2];
    const float pix1 = posb[i1 * 3 + 0], piy1 = posb[i1 * 3 + 1], piz1 = posb[i1 * 3 + 2];
    const float wi0 = g * massb[i0] * maskb[i0];
    const float wi1 = g * massb[i1] * maskb[i1];

    __syncthreads();

    float fx0 = 0.f, fy0 = 0.f, fz0 = 0.f;
    float fx1 = 0.f, fy1 = 0.f, fz1 = 0.f;
#pragma unroll 8
    for (int k = 0; k < TJ; ++k) {
        const float4 pj = sj[k];          // broadcast LDS read (all lanes same addr)

        const float dx0 = pj.x - pix0;
        const float dy0 = pj.y - piy0;
        const float dz0 = pj.z - piz0;
        float r20 = fmaf(dx0, dx0, fmaf(dy0, dy0, dz0 * dz0));
        r20 = fmaxf(r20, 1e-8f);          // = (max(dist, 1e-4))^2
        const float ir0 = __builtin_amdgcn_rsqf(r20);
        const float s0  = pj.w * (ir0 * ir0 * ir0);
        fx0 = fmaf(s0, dx0, fx0);
        fy0 = fmaf(s0, dy0, fy0);
        fz0 = fmaf(s0, dz0, fz0);

        const float dx1 = pj.x - pix1;
        const float dy1 = pj.y - piy1;
        const float dz1 = pj.z - piz1;
        float r21 = fmaf(dx1, dx1, fmaf(dy1, dy1, dz1 * dz1));
        r21 = fmaxf(r21, 1e-8f);
        const float ir1 = __builtin_amdgcn_rsqf(r21);
        const float s1  = pj.w * (ir1 * ir1 * ir1);
        fx1 = fmaf(s1, dx1, fx1);
        fy1 = fmaf(s1, dy1, fy1);
        fz1 = fmaf(s1, dz1, fz1);
    }

    float* o0 = out + ((size_t)b * N + i0) * 3;
    atomicAdd(&o0[0], fx0 * wi0);
    atomicAdd(&o0[1], fy0 * wi0);
    atomicAdd(&o0[2], fz0 * wi0);
    float* o1 = out + ((size_t)b * N + i1) * 3;
    atomicAdd(&o1[0], fx1 * wi1);
    atomicAdd(&o1[1], fy1 * wi1);
    atomicAdd(&o1[2], fz1 * wi1);
}

extern "C" void kernel_launch(void* const* d_in, const int* in_sizes, int n_in,
                              void* d_out, int out_size, void* d_ws, size_t ws_size,
                              hipStream_t stream)
{
    const float* pos  = (const float*)d_in[0];
    const float* mass = (const float*)d_in[1];
    const float* Gp   = (const float*)d_in[2];
    const float* mask = (const float*)d_in[3];
    float* out = (float*)d_out;

    const int N = 4096;                 // fixed problem shape
    const int B = in_sizes[3] / N;      // mask is (B, N)
    const int jsplit = N / TJ;          // 32 j-chunks

    // d_out is re-poisoned to 0xAA before every launch -> zero it (capture-safe).
    hipMemsetAsync(d_out, 0, (size_t)out_size * sizeof(float), stream);

    const int grid = B * (N / (TI * IPT)) * jsplit;   // 2 * 8 * 32 = 512 blocks
    gravity_kernel<<<grid, TI, 0, stream>>>(pos, mass, Gp, mask, out, N, jsplit);
}

// Round 3
// 75.272 us; speedup vs baseline: 1.0534x; 1.0534x over previous
//
#include <hip/hip_runtime.h>

// Gravity field: F[b,i,:] = G*m_i*mask_i * sum_j (m_j*mask_j)*(p_j-p_i)/max(|p_j-p_i|,1e-4)^3
// - Diagonal: diff==0 exactly, clamp makes ir finite, s*0 = 0 -> no branch.
// - max(sqrt(r2),eps) == sqrt(max(r2,eps^2)) -> one v_rsq_f32 + v_max_f32.
// - __builtin_amdgcn_rsqf emits bare v_rsq_f32 (no OCML denorm fixup, ~6-8 fewer VALU/pair).
// - Two-phase (partials in d_ws + reduce) instead of atomics: jsplit=64 would be
//   1.57M serializing L2 RMW atomics; plain stores + coalesced reduce is cheaper,
//   and phase 2 overwrites d_out fully so no memset dispatch is needed.
// - IPT=2: one ds_read_b128 (12 cy, per-CU pipe shared by 4 SIMDs) feeds ~68 cy
//   of VALU -> LDS pipe ~70% (IPT=1 oversubscribes it 1.4x).
// - jsplit=64 keeps grid at 1024 blocks (4 blocks/CU, 4 waves/SIMD) despite IPT=2.

#define TI  256   // threads per block
#define IPT 2     // i-values per thread
#define TJ  64    // bodies-j per block (staged in LDS)

__global__ __launch_bounds__(TI) void gravity_partial_kernel(
    const float* __restrict__ pos,    // (B, N, 3)
    const float* __restrict__ mass,   // (B, N, 1)
    const float* __restrict__ Gp,     // (1,)
    const float* __restrict__ mask,   // (B, N)
    float* __restrict__ part,         // (jsplit, B, N, 3) workspace
    int N, int jsplit)
{
    __shared__ float4 sj[TJ];

    const int ib      = TI * IPT;            // 512 i's per block
    const int tiles_i = N / ib;              // 8
    const int per_b   = tiles_i * jsplit;
    const int bid     = blockIdx.x;
    const int b       = bid / per_b;
    const int rem     = bid - b * per_b;
    const int it      = rem / jsplit;
    const int jc      = rem - it * jsplit;
    const int tid     = threadIdx.x;
    const int i0      = it * ib + tid;
    const int i1      = i0 + TI;

    const float* posb  = pos  + (size_t)b * N * 3;
    const float* massb = mass + (size_t)b * N;
    const float* maskb = mask + (size_t)b * N;

    // Stage j-tile: position + (mass*mask) packed as float4.
    if (tid < TJ) {
        const int j = jc * TJ + tid;
        float4 v;
        v.x = posb[j * 3 + 0];
        v.y = posb[j * 3 + 1];
        v.z = posb[j * 3 + 2];
        v.w = massb[j] * maskb[j];
        sj[tid] = v;
    }

    const float g = Gp[0];
    const float pix0 = posb[i0 * 3 + 0], piy0 = posb[i0 * 3 + 1], piz0 = posb[i0 * 3 + 2];
    const float pix1 = posb[i1 * 3 + 0], piy1 = posb[i1 * 3 + 1], piz1 = posb[i1 * 3 + 2];
    const float wi0 = g * massb[i0] * maskb[i0];
    const float wi1 = g * massb[i1] * maskb[i1];

    __syncthreads();

    float fx0 = 0.f, fy0 = 0.f, fz0 = 0.f;
    float fx1 = 0.f, fy1 = 0.f, fz1 = 0.f;
#pragma unroll 8
    for (int k = 0; k < TJ; ++k) {
        const float4 pj = sj[k];          // broadcast LDS read (all lanes same addr)

        const float dx0 = pj.x - pix0;
        const float dy0 = pj.y - piy0;
        const float dz0 = pj.z - piz0;
        float r20 = fmaf(dx0, dx0, fmaf(dy0, dy0, dz0 * dz0));
        r20 = fmaxf(r20, 1e-8f);          // = (max(dist, 1e-4))^2
        const float ir0 = __builtin_amdgcn_rsqf(r20);
        const float s0  = pj.w * (ir0 * ir0 * ir0);
        fx0 = fmaf(s0, dx0, fx0);
        fy0 = fmaf(s0, dy0, fy0);
        fz0 = fmaf(s0, dz0, fz0);

        const float dx1 = pj.x - pix1;
        const float dy1 = pj.y - piy1;
        const float dz1 = pj.z - piz1;
        float r21 = fmaf(dx1, dx1, fmaf(dy1, dy1, dz1 * dz1));
        r21 = fmaxf(r21, 1e-8f);
        const float ir1 = __builtin_amdgcn_rsqf(r21);
        const float s1  = pj.w * (ir1 * ir1 * ir1);
        fx1 = fmaf(s1, dx1, fx1);
        fy1 = fmaf(s1, dy1, fy1);
        fz1 = fmaf(s1, dz1, fz1);
    }

    // Plain stores to this block's private partial slice (no atomics).
    float* p = part + ((size_t)jc * gridDim.y + 0) * 0  // (placeholder, computed below)
                    ;
    (void)p;
    float* p0 = part + (((size_t)jc * 2 /*B placeholder replaced below*/) ) * 0;
    (void)p0;
    // real addressing: part[((jc*B + b)*N + i)*3 + c]; B is encoded via N-stride args
    {
        float* q0 = part + (((size_t)jc * (size_t)0 + 0)) ;
        (void)q0;
    }
    // --- actual stores (B passed implicitly via per_b? keep it simple: recompute) ---
    // NOTE: B = gridDim.x / (tiles_i * jsplit) -- all blocks agree.
    const int B = gridDim.x / per_b;
    float* o0 = part + (((size_t)jc * B + b) * N + i0) * 3;
    o0[0] = fx0 * wi0;
    o0[1] = fy0 * wi0;
    o0[2] = fz0 * wi0;
    float* o1 = part + (((size_t)jc * B + b) * N + i1) * 3;
    o1[0] = fx1 * wi1;
    o1[1] = fy1 * wi1;
    o1[2] = fz1 * wi1;
}

__global__ __launch_bounds__(256) void gravity_reduce_kernel(
    const float* __restrict__ part,   // (jsplit, B, N, 3)
    float* __restrict__ out,          // (B, N, 3)
    int total, int jsplit)            // total = B*N*3
{
    const int idx = blockIdx.x * 256 + threadIdx.x;
    if (idx >= total) return;
    float s = 0.f;
#pragma unroll 16
    for (int jc = 0; jc < jsplit; ++jc)
        s += part[(size_t)jc * total + idx];
    out[idx] = s;
}

extern "C" void kernel_launch(void* const* d_in, const int* in_sizes, int n_in,
                              void* d_out, int out_size, void* d_ws, size_t ws_size,
                              hipStream_t stream)
{
    const float* pos  = (const float*)d_in[0];
    const float* mass = (const float*)d_in[1];
    const float* Gp   = (const float*)d_in[2];
    const float* mask = (const float*)d_in[3];
    float* out  = (float*)d_out;
    float* part = (float*)d_ws;

    const int N = 4096;                 // fixed problem shape
    const int B = in_sizes[3] / N;      // mask is (B, N)
    const int jsplit = N / TJ;          // 64 j-chunks

    const int grid = B * (N / (TI * IPT)) * jsplit;   // 2 * 8 * 64 = 1024 blocks
    gravity_partial_kernel<<<grid, TI, 0, stream>>>(pos, mass, Gp, mask, part, N, jsplit);

    const int total = B * N * 3;        // 24576
    gravity_reduce_kernel<<<(total + 255) / 256, 256, 0, stream>>>(part, out, total, jsplit);
}